// Round 12
// baseline (174.859 us; speedup 1.0000x reference)
//
#include <hip/hip_runtime.h>
#include <stdint.h>

#define M_DIM 2048
#define N_DIM 4096
#define K_DIM 4096
#define NGROUP 32
#define GSIZE 128

#define RQ_UP   (127.0f / 15.0f)   // weight requant gain
#define RQ_DOWN (15.0f / 127.0f)

// ---------------------------------------------------------------------------
// R11 (resubmit — R11 bench was an infra failure, kernel audited clean):
// R10's compiler-proof zero-LDS pipeline + TLP. 8 free-running waves
// (512 thr) per block, wave tile 64x64 (4x4 frags of 16x16x64 i8), 2 waves
// per SIMD, NO barriers in the K-loop: when a wave stalls in its counted
// WAITVM, its SIMD-mate issues MFMAs (m114 overlap — R0-R7's barriers
// prevented this; R10 had the pipeline but only 1 wave/SIMD so vmcnt stalls
// were exposed: 1620 cyc/step vs 653 MFMA floor = delivery-throughput gap).
// Loads stay opaque asm global_load_dwordx4 with bare counted vmcnt
// (R10-proven: compiler cannot collapse the dbuf). Depth-3 sets, 8 loads/
// set -> steady vmcnt(16), tail 16/8/0. Regs/wave ~180 <= 256 (2/SIMD).
// k-tiled pre-swizzled A8/Bt8 layout (R8/R9-verified) -> 1 KiB coalesced
// fragment blocks. Grid 16x16, block tile 128x256 = 1 block/CU.
// ---------------------------------------------------------------------------
#define BM 128
#define BN 256
#define NSLICE (K_DIM / 64)        // 64

typedef __attribute__((ext_vector_type(4))) int int32x4_t;

#define WAITVM_(N) asm volatile("s_waitcnt vmcnt(" #N ")")
#define WAITVM(N)                                   \
    do {                                            \
        __builtin_amdgcn_sched_barrier(0);          \
        WAITVM_(N);                                 \
        __builtin_amdgcn_sched_barrier(0);          \
    } while (0)

// ---------------------------------------------------------------------------
// Fused prep (identical to R8/R9/R10 — verified):
//   [0, 2048): per-token activation quant -> A8 tiled, xscale, czp
//   [2048, ..): weight requant -> Bt8 tiled + group sums Sw.
// Tiled layout: tile (rt, kt) at ((rt*64 + kt) * 8192); row r at r*64;
// 16B chunk c of the 64B k-slice at slot c ^ ((r>>1)&3) (bijective in 1KB).
// ---------------------------------------------------------------------------
#define QUANT_BLOCKS M_DIM
#define DEQ_BLOCKS ((N_DIM * K_DIM) / 8 / 256)       // 8 codes / thread

__global__ __launch_bounds__(256) void prep_kernel(
        const float* __restrict__ x,
        const int* __restrict__ qw,          // [N][K] codes 0..15 as int32
        const float* __restrict__ wsc,       // [N][32]
        const int* __restrict__ wzp,         // [N][32]
        char* __restrict__ A8,               // tiled [16][64][128][64]
        char* __restrict__ Bt8,              // tiled [32][64][128][64]
        float* __restrict__ xscale,          // [M]
        float* __restrict__ xzpc,            // [M]  = 128 - zp
        int* __restrict__ Sw)                // [N][32] group sums of Bt8
{
    const int t = threadIdx.x;
    if (blockIdx.x < QUANT_BLOCKS) {
        const int s = blockIdx.x;
        const float* xrow = x + (size_t)s * K_DIM;

        float xv[16];
        float vmin = 1e38f, vmax = -1e38f;
#pragma unroll
        for (int p = 0; p < 4; ++p) {
            float4 v = *((const float4*)(xrow + p * 1024) + t);
            xv[p*4+0] = v.x; xv[p*4+1] = v.y; xv[p*4+2] = v.z; xv[p*4+3] = v.w;
            vmin = fminf(vmin, fminf(fminf(v.x, v.y), fminf(v.z, v.w)));
            vmax = fmaxf(vmax, fmaxf(fmaxf(v.x, v.y), fmaxf(v.z, v.w)));
        }
#pragma unroll
        for (int off = 32; off > 0; off >>= 1) {
            vmin = fminf(vmin, __shfl_xor(vmin, off));
            vmax = fmaxf(vmax, __shfl_xor(vmax, off));
        }
        __shared__ float smin[4], smax[4];
        const int wave = t >> 6;
        if ((t & 63) == 0) { smin[wave] = vmin; smax[wave] = vmax; }
        __syncthreads();
        vmin = fminf(fminf(smin[0], smin[1]), fminf(smin[2], smin[3]));
        vmax = fmaxf(fmaxf(smax[0], smax[1]), fmaxf(smax[2], smax[3]));

        float sc = (vmax - vmin) / 255.0f;
        sc = fmaxf(sc, 1e-5f);
        float zp = rintf(-vmin / sc);
        zp = fminf(fmaxf(zp, 0.0f), 255.0f);
        const float inv_sc = 1.0f / sc;

        const int r   = s & 127;
        const int mt  = s >> 7;
        const int swr = (r >> 1) & 3;
#pragma unroll
        for (int p = 0; p < 4; ++p) {
            int b[4];
#pragma unroll
            for (int e = 0; e < 4; ++e) {
                float q = fminf(fmaxf(rintf(xv[p*4+e] * inv_sc) + zp, 0.0f), 255.0f);
                b[e] = (int)q - 128;
            }
            unsigned pack = (b[0] & 0xff) | ((b[1] & 0xff) << 8) |
                            ((b[2] & 0xff) << 16) | ((b[3] & 0xff) << 24);
            const int kt   = p * 16 + (t >> 4);
            const int slot = ((t >> 2) & 3) ^ swr;
            *(unsigned*)(A8 + (((size_t)(mt * 64 + kt)) << 13)
                            + r * 64 + slot * 16 + (t & 3) * 4) = pack;
        }
        if (t == 0) { xscale[s] = sc; xzpc[s] = 128.0f - zp; }
    } else {
        // ---- weight requant: 8 codes/thread; 16-lane cluster = 1 group ----
        const size_t base = ((size_t)(blockIdx.x - QUANT_BLOCKS) * 256 + t) * 8;
        const int n = (int)(base >> 12);          // /4096
        const int g = (int)((base >> 7) & 31);
        const int zp = wzp[n * NGROUP + g];

        // inline rsn: row max of the 32 scales across the 16-lane cluster
        const int cl = t & 15;
        float2 wp = *(const float2*)(wsc + (size_t)n * NGROUP + cl * 2);
        float smx = fmaxf(wp.x, wp.y);
#pragma unroll
        for (int off = 1; off < 16; off <<= 1)
            smx = fmaxf(smx, __shfl_xor(smx, off));
        const float factor = wsc[n * NGROUP + g] * (RQ_UP / smx);   // <= 127/15

        int4 c0 = *(const int4*)(qw + base);
        int4 c1 = *(const int4*)(qw + base + 4);
        int w[8];
        w[0] = (int)rintf((float)(c0.x - zp) * factor);
        w[1] = (int)rintf((float)(c0.y - zp) * factor);
        w[2] = (int)rintf((float)(c0.z - zp) * factor);
        w[3] = (int)rintf((float)(c0.w - zp) * factor);
        w[4] = (int)rintf((float)(c1.x - zp) * factor);
        w[5] = (int)rintf((float)(c1.y - zp) * factor);
        w[6] = (int)rintf((float)(c1.z - zp) * factor);
        w[7] = (int)rintf((float)(c1.w - zp) * factor);
        uint2 pk;
        pk.x = (w[0] & 0xff) | ((w[1] & 0xff) << 8) | ((w[2] & 0xff) << 16) | ((w[3] & 0xff) << 24);
        pk.y = (w[4] & 0xff) | ((w[5] & 0xff) << 8) | ((w[6] & 0xff) << 16) | ((w[7] & 0xff) << 24);

        const int r  = n & 127;
        const int nt = n >> 7;
        const int kt = (int)((base >> 6) & 63);
        const int slot = (int)(((base >> 4) & 3)) ^ ((r >> 1) & 3);
        *(uint2*)(Bt8 + (((size_t)(nt * 64 + kt)) << 13)
                      + r * 64 + slot * 16 + (int)(base & 15)) = pk;

        int s8 = w[0] + w[1] + w[2] + w[3] + w[4] + w[5] + w[6] + w[7];
#pragma unroll
        for (int off = 1; off < 16; off <<= 1) s8 += __shfl_xor(s8, off);
        if ((t & 15) == 0)
            Sw[n * NGROUP + g] = s8;     // coalesced, no atomic
    }
}

// ---------------------------------------------------------------------------
// Zero-LDS i8 GEMM, 8 free-running waves (2/SIMD), depth-3 asm pipeline.
// Epilogue: out[m][n] = xscale[m]*(fws[n]*iacc + czp[m]*WSf[n]) + bias[n]
// ---------------------------------------------------------------------------
__global__ __launch_bounds__(512, 1) void gemm_kernel(
        const char* __restrict__ A8,     // tiled [16][64][128][64]
        const char* __restrict__ Bt8,    // tiled [32][64][128][64]
        const float* __restrict__ xscale,
        const float* __restrict__ xzpc,
        const float* __restrict__ wsc,   // [N][32]
        const int* __restrict__ Sw,      // [N][32]
        const float* __restrict__ bias,  // [N]
        float* __restrict__ out)         // [M][N] f32
{
    __shared__ float fws_s[BN], wsf_s[BN];   // epilogue constants only

    const int tid  = threadIdx.x;
    const int bn   = blockIdx.x;         // 0..15 -> 256-col band
    const int bm   = blockIdx.y;         // 0..15 -> 128-row tile
    const int wave = tid >> 6;           // 0..7
    const int lane = tid & 63;
    const int wr   = wave >> 2;          // 0..1 -> 64-row band
    const int wcl  = wave & 3;           // 0..3 -> 64-col band
    const int lrow  = lane & 15;
    const int lquad = lane >> 4;         // 0..3 -> 16B k-chunk

    // --- per-column epilogue constants: threads 0..255 own column tid ---
    if (tid < BN) {
        const int n = bn * BN + tid;
        const int4* s4 = (const int4*)(Sw + (size_t)n * NGROUP);
        int acc = 0;
#pragma unroll
        for (int p = 0; p < 8; ++p) { int4 v = s4[p]; acc += v.x + v.y + v.z + v.w; }
        const float4* w4 = (const float4*)(wsc + (size_t)n * NGROUP);
        float s = 0.f;
#pragma unroll
        for (int p = 0; p < 8; ++p) {
            float4 w = w4[p];
            s = fmaxf(s, fmaxf(fmaxf(w.x, w.y), fmaxf(w.z, w.w)));
        }
        const float fw = s * RQ_DOWN;
        fws_s[tid] = fw;
        wsf_s[tid] = fw * (float)acc;
    }
    // clean vmcnt baseline: counted waits below assume only frag loads live
    __builtin_amdgcn_sched_barrier(0);
    asm volatile("s_waitcnt vmcnt(0) lgkmcnt(0)");
    __builtin_amdgcn_sched_barrier(0);

    // --- per-lane fragment bases (R9/R10-verified address math).
    // A: tile bm, rows wr*64 + i*16 + lrow         -> frag i at +i*1024
    // B: tile bn*2 + (wcl>>1), rows (wcl&1)*64 + j*16 + lrow -> +j*1024
    const int xq = (lquad ^ ((lrow >> 1) & 3)) * 16;
    const char* pA = A8 + ((size_t)bm << 19)
                        + (size_t)(wr * 64 + lrow) * 64 + xq;
    const char* pB = Bt8 + ((size_t)(bn * 2 + (wcl >> 1)) << 19)
                        + (size_t)((wcl & 1) * 64 + lrow) * 64 + xq;

    int32x4_t iacc[4][4];
    const int32x4_t zi = {0, 0, 0, 0};
#pragma unroll
    for (int i = 0; i < 4; ++i)
#pragma unroll
        for (int j = 0; j < 4; ++j) iacc[i][j] = zi;

    // Opaque asm loads: 8x global_load_dwordx4 (4 A + 4 B frags = one slice
    // for this wave). Early-clobber outs; completion only via counted WAITVM.
#define LOADF(s, aF, bF) {                                            \
        const char* a_ = pA + ((size_t)(s) << 13);                    \
        const char* b_ = pB + ((size_t)(s) << 13);                    \
        asm volatile(                                                 \
            "global_load_dwordx4 %0, %8, off\n\t"                     \
            "global_load_dwordx4 %1, %8, off offset:1024\n\t"         \
            "global_load_dwordx4 %2, %8, off offset:2048\n\t"         \
            "global_load_dwordx4 %3, %8, off offset:3072\n\t"         \
            "global_load_dwordx4 %4, %9, off\n\t"                     \
            "global_load_dwordx4 %5, %9, off offset:1024\n\t"         \
            "global_load_dwordx4 %6, %9, off offset:2048\n\t"         \
            "global_load_dwordx4 %7, %9, off offset:3072"             \
            : "=&v"(aF[0]), "=&v"(aF[1]), "=&v"(aF[2]), "=&v"(aF[3]), \
              "=&v"(bF[0]), "=&v"(bF[1]), "=&v"(bF[2]), "=&v"(bF[3])  \
            : "v"(a_), "v"(b_));                                      \
    }

#define MFMAS(aF, bF) {                                               \
        _Pragma("unroll")                                             \
        for (int i_ = 0; i_ < 4; ++i_)                                \
            _Pragma("unroll")                                         \
            for (int j_ = 0; j_ < 4; ++j_)                            \
                iacc[i_][j_] = __builtin_amdgcn_mfma_i32_16x16x64_i8( \
                    aF[i_], bF[j_], iacc[i_][j_], 0, 0, 0);           \
    }

    int32x4_t aX[4], bX[4], aY[4], bY[4], aZ[4], bZ[4];

    // ---- depth-3 pipeline: 24 loads in flight, vmcnt(16) steady ----
    LOADF(0, aX, bX);
    LOADF(1, aY, bY);
    LOADF(2, aZ, bZ);
#pragma unroll 1
    for (int s = 0; s < NSLICE - 4; s += 3) {
        WAITVM(16); MFMAS(aX, bX); LOADF(s + 3, aX, bX);
        WAITVM(16); MFMAS(aY, bY); LOADF(s + 4, aY, bY);
        WAITVM(16); MFMAS(aZ, bZ); LOADF(s + 5, aZ, bZ);
    }
    // tail: slices 60..63 (hand-verified counts)
    WAITVM(16); MFMAS(aX, bX); LOADF(63, aX, bX);
    WAITVM(16); MFMAS(aY, bY);           // slice 61
    WAITVM(8);  MFMAS(aZ, bZ);           // slice 62
    WAITVM(0);  MFMAS(aX, bX);           // slice 63

    __syncthreads();             // publish fws_s / wsf_s (only barrier)

    // --- epilogue: C/D layout col=lane&15, row=lquad*4+reg ---
    float fn[4], wf[4], bb[4];
    int ncol[4];
#pragma unroll
    for (int j = 0; j < 4; ++j) {
        const int ncl = wcl * 64 + j * 16 + lrow;
        ncol[j] = bn * BN + ncl;
        fn[j] = fws_s[ncl];
        wf[j] = wsf_s[ncl];
        bb[j] = bias[ncol[j]];
    }
    const int m0 = bm * BM + wr * 64;
#pragma unroll
    for (int i = 0; i < 4; ++i) {
#pragma unroll
        for (int r = 0; r < 4; ++r) {
            const int m = m0 + i * 16 + lquad * 4 + r;
            const float xs  = xscale[m];
            const float czp = xzpc[m];
            float* orow = out + (size_t)m * N_DIM;
#pragma unroll
            for (int j = 0; j < 4; ++j)
                orow[ncol[j]] = xs * (fn[j] * (float)iacc[i][j][r] + czp * wf[j]) + bb[j];
        }
    }
#undef MFMAS
#undef LOADF
}

extern "C" void kernel_launch(void* const* d_in, const int* in_sizes, int n_in,
                              void* d_out, int out_size, void* d_ws, size_t ws_size,
                              hipStream_t stream) {
    const float* x     = (const float*)d_in[0];
    const int*   qw    = (const int*)d_in[1];
    const float* wsc   = (const float*)d_in[2];
    const int*   wzp   = (const int*)d_in[3];
    const float* bias  = (const float*)d_in[4];
    float* out = (float*)d_out;

    // workspace layout
    char* A8  = (char*)d_ws;                                   //  8 MiB (tiled)
    char* Bt8 = A8 + (size_t)M_DIM * K_DIM;                    // 16 MiB (tiled)
    float* xscale = (float*)(Bt8 + (size_t)N_DIM * K_DIM);     //  8 KiB
    float* xzpc   = xscale + M_DIM;                            //  8 KiB
    int*   Sw     = (int*)(xzpc + M_DIM);                      // 512 KiB

    prep_kernel<<<QUANT_BLOCKS + DEQ_BLOCKS, 256, 0, stream>>>(
        x, qw, wsc, wzp, A8, Bt8, xscale, xzpc, Sw);

    dim3 grid(N_DIM / BN, M_DIM / BM);                          // 16 x 16
    gemm_kernel<<<grid, 512, 0, stream>>>(
        A8, Bt8, xscale, xzpc, wsc, Sw, bias, out);
}